// Round 6
// baseline (395.629 us; speedup 1.0000x reference)
//
#include <hip/hip_runtime.h>

typedef unsigned short ushort_t;
typedef __attribute__((ext_vector_type(8))) __bf16 bf16x8;
typedef __attribute__((ext_vector_type(4))) float f32x4;
typedef __attribute__((ext_vector_type(4))) int i32x4;
typedef __attribute__((ext_vector_type(4))) unsigned short u16x4;
typedef __attribute__((ext_vector_type(8))) unsigned short u16x8;

__device__ __forceinline__ float bf2f(ushort_t u) {
  union { unsigned u32; float f; } c; c.u32 = ((unsigned)u) << 16; return c.f;
}
__device__ __forceinline__ ushort_t f2bf(float f) {
  union { float f; unsigned u32; } c; c.f = f;
  unsigned u = c.u32;
  u += 0x7fffu + ((u >> 16) & 1u);
  return (ushort_t)(u >> 16);
}

__device__ __forceinline__ void gload_lds16(const void* g, void* l) {
  __builtin_amdgcn_global_load_lds(
      (const __attribute__((address_space(1))) void*)g,
      (__attribute__((address_space(3))) void*)l,
      16, 0, 0);
}

// Stage one 128x64 bf16 half-tile: linear LDS dest, inverse-swizzled global src
__device__ __forceinline__ void stage_half(const char* gbase, long row0, int ldbytes,
                                           int kbyte, char* lds_half, int tid)
{
  const int rl = tid >> 3;
  const int cs = ((tid & 7) ^ (rl & 7)) << 4;
  const char* g0 = gbase + (row0 + rl) * (long)ldbytes + kbyte + cs;
  char* l0 = lds_half + ((tid >> 6) << 10);
  gload_lds16(g0, l0);
  gload_lds16(g0 + (long)ldbytes * 64, l0 + 8192);
}

#define BAR() __builtin_amdgcn_s_barrier()
#define VMW4() asm volatile("s_waitcnt vmcnt(4)" ::: "memory")
#define VMW6() asm volatile("s_waitcnt vmcnt(6)" ::: "memory")
#define PR1() __builtin_amdgcn_s_setprio(1)
#define PR0() __builtin_amdgcn_s_setprio(0)

#define READ_A(dst, Abase, mb) \
  _Pragma("unroll") for (int m_ = 0; m_ < 4; ++m_) { \
    const char* p_ = (Abase) + ((wr << 7) + (mb) + m_ * 16 + fr) * 128; \
    dst[m_][0] = *(const bf16x8*)(p_ + ch0); \
    dst[m_][1] = *(const bf16x8*)(p_ + ch1); }

// ===========================================================================
// gemm256: 256x256 bf16 NT GEMM, 8-phase (T2 swizzle + T3/T4 + T5).
// BK=64, 8 waves (2Mx4N), per-wave 128x64. QKV (fused, MAPQ=2) / FFN (MAPQ=1).
// ===========================================================================
#define READ_B4(dst, Bbase, jb) \
  _Pragma("unroll") for (int n_ = 0; n_ < 2; ++n_) { \
    const char* p_ = (Bbase) + ((wc << 6) + (jb) + n_ * 16 + fr) * 128; \
    dst[n_][0] = *(const bf16x8*)(p_ + ch0); \
    dst[n_][1] = *(const bf16x8*)(p_ + ch1); }

#define MFMA_Q(ib, jb, aarr, barr) \
  _Pragma("unroll") for (int m_ = 0; m_ < 4; ++m_) \
  _Pragma("unroll") for (int n_ = 0; n_ < 2; ++n_) \
  _Pragma("unroll") for (int s_ = 0; s_ < 2; ++s_) \
    acc[(ib) + m_][(jb) + n_] = __builtin_amdgcn_mfma_f32_16x16x32_bf16( \
        aarr[m_][s_], barr[n_][s_], acc[(ib) + m_][(jb) + n_], 0, 0, 0);

#define STAGE_A(t, h, db) stage_half(gA, m0 + (h) * 128, ldab, (t) << 7, \
    (char*)lds + (db) * 32768 + (h) * 16384, tid)
#define STAGE_B(t, h, db) stage_half(gB, n0 + (h) * 128, ldbb, (t) << 7, \
    (char*)lds + 65536 + (db) * 32768 + (h) * 16384, tid)

template<int EPI, int MAPQ, bool ROUTE>
__global__ __launch_bounds__(512, 1) void gemm256(
    const ushort_t* __restrict__ A, int lda,
    const ushort_t* __restrict__ B, int ldb,
    ushort_t* __restrict__ C0, ushort_t* __restrict__ C1, ushort_t* __restrict__ C2,
    int ldc, const float* __restrict__ bias, float scale, int K)
{
  __shared__ __attribute__((aligned(16))) ushort_t lds[65536];

  int bx, by;
  if (MAPQ == 1) {
    const int flat = blockIdx.y * 4 + blockIdx.x;       // grid 4x64
    by = ((flat >> 5) << 3) | (flat & 7);
    bx = (flat >> 3) & 3;
  } else if (MAPQ == 2) {                               // grid 768 linear
    const int l = blockIdx.x;
    const int c = l & 7, u = l >> 3;
    const int q12 = u / 12;
    by = (q12 << 3) | c;
    bx = u - q12 * 12;
  } else { bx = blockIdx.x; by = blockIdx.y; }

  const int NT = K >> 6;
  const int NIT = NT >> 1, NTm1 = NT - 1;

  const int tid = threadIdx.x;
  const int lane = tid & 63, fr = lane & 15, g = lane >> 4, lm = lane & 7;
  const int wv = tid >> 6, wr = wv >> 2, wc = wv & 3;
  const long m0 = (long)by << 8, n0 = (long)bx << 8;

  const char* gA = (const char*)A;
  const char* gB = (const char*)B;
  const int ldab = lda << 1, ldbb = ldb << 1;

  const int ch0 = (g ^ lm) << 4;
  const int ch1 = ((4 | g) ^ lm) << 4;

  const char* A0 = (const char*)lds;
  const char* A1 = (const char*)lds + 32768;
  const char* B0 = (const char*)lds + 65536;
  const char* B1 = (const char*)lds + 98304;

  f32x4 acc[8][4] = {};
  bf16x8 aF[4][2], aG[4][2], bX[2][2];

  STAGE_A(0, 0, 0); STAGE_A(0, 1, 0); STAGE_B(0, 0, 0); STAGE_B(0, 1, 0);
  STAGE_A(1, 0, 1); STAGE_A(1, 1, 1);
  VMW4(); BAR();

  for (int i = 0; i < NIT; ++i) {
    const int t1 = 2 * i + 1;
    const int t2 = (2 * i + 2 < NTm1) ? 2 * i + 2 : NTm1;
    const int t3 = (2 * i + 3 < NTm1) ? 2 * i + 3 : NTm1;

    READ_A(aF, A0, 0); READ_B4(bX, B0, 0);
    STAGE_B(t1, 0, 1);
    BAR(); PR1(); MFMA_Q(0, 0, aF, bX); PR0(); BAR();

    READ_A(aG, A0, 64);
    STAGE_B(t1, 1, 1);
    BAR(); PR1(); MFMA_Q(4, 0, aG, bX); PR0(); BAR();

    READ_B4(bX, B0, 32);
    STAGE_A(t2, 0, 0);
    BAR(); PR1(); MFMA_Q(4, 2, aG, bX); PR0(); BAR();

    STAGE_A(t2, 1, 0);
    BAR(); PR1(); MFMA_Q(0, 2, aF, bX); PR0(); VMW4(); BAR();

    READ_A(aF, A1, 0); READ_B4(bX, B1, 0);
    STAGE_B(t2, 0, 0);
    BAR(); PR1(); MFMA_Q(0, 0, aF, bX); PR0(); BAR();

    READ_A(aG, A1, 64);
    STAGE_B(t2, 1, 0);
    BAR(); PR1(); MFMA_Q(4, 0, aG, bX); PR0(); BAR();

    READ_B4(bX, B1, 32);
    STAGE_A(t3, 0, 1);
    BAR(); PR1(); MFMA_Q(4, 2, aG, bX); PR0(); BAR();

    STAGE_A(t3, 1, 1);
    BAR(); PR1(); MFMA_Q(0, 2, aF, bX); PR0(); VMW4(); BAR();
  }

  ushort_t* Cd = C0;
  long nc0 = (long)bx << 8;
  if constexpr (ROUTE) {
    const int which = bx >> 2;
    Cd = (which == 0) ? C0 : (which == 1) ? C1 : C2;
    nc0 = (long)(bx & 3) << 8;
  }

  const int cm = g << 2, cn = fr;
#pragma unroll
  for (int i2 = 0; i2 < 8; ++i2)
#pragma unroll
    for (int j2 = 0; j2 < 4; ++j2) {
      const long gm = m0 + (wr << 7) + i2 * 16 + cm;
      const long gn = nc0 + (wc << 6) + j2 * 16 + cn;
      float bv = 0.f;
      if constexpr (EPI >= 1) bv = bias[gn];
#pragma unroll
      for (int r = 0; r < 4; ++r) {
        float v = acc[i2][j2][r] * scale + bv;
        if constexpr (EPI == 2) v = fmaxf(v, 0.f);
        Cd[(gm + r) * ldc + gn] = f2bf(v);
      }
    }
}

// ===========================================================================
// gemmA: 256x128 bf16 NT GEMM, SQUARE 64x64 wave tiles (4Mx2N), BK=64,
// TRIPLE-buffered LDS (144 KiB), 2 phases/K-tile, balanced 8 ds_reads/phase,
// steady-state vmcnt(6) (tile u+1 confirmed, tile u+2 in flight).
// MAP: 1 = triangular scores grid (72 tiles/batch, grid=576, bz=bid&7),
//      2 = heavy-first PV grid (grid=512, bz=bid&7), K=(by+1)*256.
// ===========================================================================
#define RDA4(dst, base, ch) \
  _Pragma("unroll") for (int m_ = 0; m_ < 4; ++m_) \
    dst[m_] = *(const bf16x8*)((base) + ((wr4 << 6) + m_ * 16 + fr) * 128 + (ch));

#define RDB4(dst, base, ch) \
  _Pragma("unroll") for (int n_ = 0; n_ < 4; ++n_) \
    dst[n_] = *(const bf16x8*)((base) + ((wc2 << 6) + n_ * 16 + fr) * 128 + (ch));

#define MM16() \
  _Pragma("unroll") for (int m_ = 0; m_ < 4; ++m_) \
  _Pragma("unroll") for (int n_ = 0; n_ < 4; ++n_) \
    acc[m_][n_] = __builtin_amdgcn_mfma_f32_16x16x32_bf16( \
        af[m_], bfv[n_], acc[m_][n_], 0, 0, 0);

#define SA2_(t, dst) do { \
    stage_half(gA, m0, ldab, (t) << 7, (dst), tid); \
    stage_half(gA, m0 + 128, ldab, (t) << 7, (dst) + 16384, tid); } while (0)
#define SB2_(t, dst) stage_half(gB, n0, ldbb, (t) << 7, (dst), tid)

template<int EPI, int MAP, bool CKLIM>
__global__ __launch_bounds__(512, 1) void gemmA(
    const ushort_t* __restrict__ A, int lda, long bsA,
    const ushort_t* __restrict__ B, int ldb, long bsB,
    ushort_t* __restrict__ C, int ldc, long bsC,
    const float* __restrict__ bias, float scale, int K)
{
  __shared__ __attribute__((aligned(16))) ushort_t lds[73728];  // 144 KiB

  int bx, by, bz;
  if (MAP == 1) {            // scores: bz pinned, triangular within
    const int bid = blockIdx.x;
    bz = bid & 7; const int r = bid >> 3;
    by = 0; while ((by + 1) * (by + 2) <= r) ++by;
    bx = r - by * (by + 1);
  } else if (MAP == 2) {     // PV: bz pinned, heavy-first within
    const int bid = blockIdx.x;
    bz = bid & 7; const int u = bid >> 3;
    by = 7 - (u >> 3); bx = u & 7;
  } else { bx = blockIdx.x; by = blockIdx.y; bz = blockIdx.z; }

  const int NT = CKLIM ? ((by + 1) << 2) : (K >> 6);

  const int tid = threadIdx.x;
  const int lane = tid & 63, fr = lane & 15, g = lane >> 4, lm = lane & 7;
  const int wv = tid >> 6;
  const int wr4 = wv >> 1, wc2 = wv & 1;       // 4 x 2 wave grid, 64x64 tiles
  const long m0 = (long)by << 8, n0 = (long)bx << 7;

  const char* gA = (const char*)(A + bz * bsA);
  const char* gB = (const char*)(B + bz * bsB);
  const int ldab = lda << 1, ldbb = ldb << 1;

  const int ch0 = (g ^ lm) << 4;
  const int ch1 = ((4 | g) ^ lm) << 4;

  // layout: [A0 32K | B0 16K | A1 32K | B1 16K | A2 32K | B2 16K]
  char* a0 = (char*)lds;
  char* b0 = a0 + 32768;
  char* a1 = a0 + 49152;
  char* b1 = a1 + 32768;
  char* a2 = a0 + 98304;
  char* b2 = a2 + 32768;

  f32x4 acc[4][4] = {};
  bf16x8 af[4], bfv[4];

  // prologue: stage tiles 0,1 (12 loads); vmcnt(6) -> tile 0 landed
  SA2_(0, a0); SB2_(0, b0);
  SA2_(1, a1); SB2_(1, b1);
  VMW6(); BAR();

  for (int u = 0; u < NT; ++u) {
    const int t2 = (u + 2 < NT) ? u + 2 : NT - 1;   // clamped dup harmless
    // ph_a: k-half 0; stage tile u+2 into buf2 (freed after ph_b(u-1))
    RDA4(af, a0, ch0); RDB4(bfv, b0, ch0);
    SA2_(t2, a2); SB2_(t2, b2);
    BAR(); PR1(); MM16(); PR0(); BAR();
    // ph_b: k-half 1; vmcnt(6) confirms tile u+1, leaves tile u+2 in flight
    RDA4(af, a0, ch1); RDB4(bfv, b0, ch1);
    VMW6(); BAR(); PR1(); MM16(); PR0(); BAR();
    // rotate buffers
    char* ta = a0; a0 = a1; a1 = a2; a2 = ta;
    char* tb = b0; b0 = b1; b1 = b2; b2 = tb;
  }

  ushort_t* Cb = C + bz * bsC;
  const int cm = g << 2, cn = fr;
#pragma unroll
  for (int i2 = 0; i2 < 4; ++i2)
#pragma unroll
    for (int j2 = 0; j2 < 4; ++j2) {
      const long gm = m0 + (wr4 << 6) + i2 * 16 + cm;
      const long gn = n0 + (wc2 << 6) + j2 * 16 + cn;
      float bv = 0.f;
      if constexpr (EPI >= 1) bv = bias[gn];
#pragma unroll
      for (int r = 0; r < 4; ++r) {
        float v = acc[i2][j2][r] * scale + bv;
        if constexpr (EPI == 2) v = fmaxf(v, 0.f);
        Cb[(gm + r) * ldc + gn] = f2bf(v);
      }
    }
}

// ---------------------------------------------------------------------------
// 64x64 bf16 transpose: Vt[d][s] = V[s][d]
// ---------------------------------------------------------------------------
__global__ __launch_bounds__(256) void transpose_bf16(
    const ushort_t* __restrict__ V, int ldv, long bsV,
    ushort_t* __restrict__ Vt, int ldt, long bsT)
{
  __shared__ __attribute__((aligned(16))) ushort_t tile[64][72];
  const int bz = blockIdx.z;
  const ushort_t* Vb = V + bz * bsV;
  ushort_t* Tb = Vt + bz * bsT;
  const long s0 = (long)blockIdx.y << 6;
  const long d0 = (long)blockIdx.x << 6;
  const int tid = threadIdx.x;
  const int r = tid >> 3, c = tid & 7;
#pragma unroll
  for (int h = 0; h < 2; ++h) {
    const int rr = r + h * 32;
    i32x4 v = *(const i32x4*)(Vb + (s0 + rr) * ldv + d0 + c * 8);
    *(i32x4*)&tile[rr][c * 8] = v;
  }
  __syncthreads();
#pragma unroll
  for (int h = 0; h < 2; ++h) {
    const int dr = r + h * 32;
    union { ushort_t u[8]; i32x4 v; } t;
#pragma unroll
    for (int j = 0; j < 8; ++j) t.u[j] = tile[c * 8 + j][dr];
    *(i32x4*)(Tb + (d0 + dr) * ldt + s0 + c * 8) = t.v;
  }
}

// ---------------------------------------------------------------------------
// Row softmax, register-resident; loads/stores bounded to rup (256-granular).
// ---------------------------------------------------------------------------
__global__ __launch_bounds__(256) void softmax_sit(ushort_t* __restrict__ S,
                                                   const float* __restrict__ sit)
{
  __shared__ float red[4];
  const long row = blockIdx.x;
  const int b = (int)(row >> 11);
  const int t = (int)(row & 2047);
  const int n = t + 1;
  const int rup = ((t >> 8) + 1) << 8;
  ushort_t* Srow = S + (row << 11);
  const int tid = threadIdx.x;
  const int i0 = tid << 3;
  const bool act = i0 < rup;

  u16x8 raw = {};
  if (act) raw = *(const u16x8*)(Srow + i0);
  float v[8];
#pragma unroll
  for (int j = 0; j < 8; ++j) v[j] = bf2f(raw[j]);

  float mloc = -3.0e38f;
#pragma unroll
  for (int j = 0; j < 8; ++j) if (i0 + j < n) mloc = fmaxf(mloc, v[j]);
#pragma unroll
  for (int o = 32; o > 0; o >>= 1) mloc = fmaxf(mloc, __shfl_down(mloc, o, 64));
  if ((tid & 63) == 0) red[tid >> 6] = mloc;
  __syncthreads();
  const float m = fmaxf(fmaxf(red[0], red[1]), fmaxf(red[2], red[3]));
  __syncthreads();

  float e[8];
  float sloc = 0.f;
#pragma unroll
  for (int j = 0; j < 8; ++j) {
    e[j] = (i0 + j < n) ? __expf(v[j] - m) : 0.f;
    sloc += e[j];
  }
#pragma unroll
  for (int o = 32; o > 0; o >>= 1) sloc += __shfl_down(sloc, o, 64);
  if ((tid & 63) == 0) red[tid >> 6] = sloc;
  __syncthreads();
  const float l = red[0] + red[1] + red[2] + red[3];

  float inv = 1.f / l;
  if (sit[row] == 0.f) inv = 0.f;
  if (act) {
    const float* sitb = sit + ((long)b << 11) + i0;
    u16x8 out;
#pragma unroll
    for (int j = 0; j < 8; ++j) {
      const float p = (i0 + j < n && sitb[j] != 0.f) ? e[j] * inv : 0.f;
      out[j] = f2bf(p);
    }
    *(u16x8*)(Srow + i0) = out;
  }
}

// ---------------------------------------------------------------------------
// out = LN(xin + res) * g + b ; D = 1024, one block per row
// ---------------------------------------------------------------------------
template<bool RES_F32, bool OUT_F32>
__global__ __launch_bounds__(256) void resid_ln(
    const ushort_t* __restrict__ xin, const void* __restrict__ resv,
    const float* __restrict__ g, const float* __restrict__ be, void* __restrict__ outv)
{
  __shared__ float red[4];
  const long base = (long)blockIdx.x << 10;
  const int tid = threadIdx.x;
  const int i0 = tid << 2;

  const u16x4 xa = *(const u16x4*)(xin + base + i0);
  float v[4];
  if constexpr (RES_F32) {
    const float4 rv = *(const float4*)((const float*)resv + base + i0);
    v[0] = bf2f(xa.x) + rv.x; v[1] = bf2f(xa.y) + rv.y;
    v[2] = bf2f(xa.z) + rv.z; v[3] = bf2f(xa.w) + rv.w;
  } else {
    const u16x4 rb = *(const u16x4*)((const ushort_t*)resv + base + i0);
    v[0] = bf2f(xa.x) + bf2f(rb.x); v[1] = bf2f(xa.y) + bf2f(rb.y);
    v[2] = bf2f(xa.z) + bf2f(rb.z); v[3] = bf2f(xa.w) + bf2f(rb.w);
  }
  float s = v[0] + v[1] + v[2] + v[3];
#pragma unroll
  for (int o = 32; o > 0; o >>= 1) s += __shfl_down(s, o, 64);
  if ((tid & 63) == 0) red[tid >> 6] = s;
  __syncthreads();
  const float mu = (red[0] + red[1] + red[2] + red[3]) * (1.f / 1024.f);
  __syncthreads();
  float s2 = 0.f;
#pragma unroll
  for (int j = 0; j < 4; ++j) { const float d = v[j] - mu; s2 += d * d; }
#pragma unroll
  for (int o = 32; o > 0; o >>= 1) s2 += __shfl_down(s2, o, 64);
  if ((tid & 63) == 0) red[tid >> 6] = s2;
  __syncthreads();
  const float rstd = rsqrtf((red[0] + red[1] + red[2] + red[3]) * (1.f / 1024.f) + 1e-5f);

  const float4 gv = *(const float4*)(g + i0);
  const float4 bv = *(const float4*)(be + i0);
  const float o0 = (v[0] - mu) * rstd * gv.x + bv.x;
  const float o1 = (v[1] - mu) * rstd * gv.y + bv.y;
  const float o2 = (v[2] - mu) * rstd * gv.z + bv.z;
  const float o3 = (v[3] - mu) * rstd * gv.w + bv.w;
  if constexpr (OUT_F32) {
    float4 ov; ov.x = o0; ov.y = o1; ov.z = o2; ov.w = o3;
    *(float4*)((float*)outv + base + i0) = ov;
  } else {
    u16x4 ob = { f2bf(o0), f2bf(o1), f2bf(o2), f2bf(o3) };
    *(u16x4*)((ushort_t*)outv + base + i0) = ob;
  }
}

__global__ __launch_bounds__(256) void cast_f32_bf16(const float* __restrict__ src,
                                                     ushort_t* __restrict__ dst, int n4)
{
  const int i = blockIdx.x * 256 + threadIdx.x;
  if (i >= n4) return;
  const float4 v = *(const float4*)(src + ((long)i << 2));
  u16x4 o = { f2bf(v.x), f2bf(v.y), f2bf(v.z), f2bf(v.w) };
  *(u16x4*)(dst + ((long)i << 2)) = o;
}

__global__ __launch_bounds__(256) void cast_w5(
    const float* __restrict__ s0, const float* __restrict__ s1,
    const float* __restrict__ s2, const float* __restrict__ s3,
    const float* __restrict__ s4, ushort_t* __restrict__ dst)
{
  const int w = blockIdx.y;
  const float* src = (w == 0) ? s0 : (w == 1) ? s1 : (w == 2) ? s2 : (w == 3) ? s3 : s4;
  const long off = (long)w << 20;
  const int i = blockIdx.x * 256 + threadIdx.x;
  const float4 v = *(const float4*)(src + ((long)i << 2));
  u16x4 o = { f2bf(v.x), f2bf(v.y), f2bf(v.z), f2bf(v.w) };
  *(u16x4*)(dst + off + ((long)i << 2)) = o;
}

// ---------------------------------------------------------------------------
// Memory plan (green since round 2):
//   d_out: [q|k] bf16 -> attb -> final fp32
//   ws R0 (64MiB): [xb|vb] -> S -> [hb|ff1];  R1 (32MiB): vt -> ff2;  R2: weights
// ---------------------------------------------------------------------------
extern "C" void kernel_launch(void* const* d_in, const int* in_sizes, int n_in,
                              void* d_out, int out_size, void* d_ws, size_t ws_size,
                              hipStream_t stream) {
  const int T = 2048, D = 1024;
  const long TD = (long)T * D;
  const long ND = 8 * TD;
  const float* x    = (const float*)d_in[0];
  const float* sit  = (const float*)d_in[1];
  const float* Wq   = (const float*)d_in[2];
  const float* Wk   = (const float*)d_in[3];
  const float* Wv   = (const float*)d_in[4];
  const float* ln1g = (const float*)d_in[5];
  const float* ln1b = (const float*)d_in[6];
  const float* Wf1  = (const float*)d_in[7];
  const float* bf1  = (const float*)d_in[8];
  const float* Wf2  = (const float*)d_in[9];
  const float* bf2  = (const float*)d_in[10];
  const float* ln2g = (const float*)d_in[11];
  const float* ln2b = (const float*)d_in[12];

  ushort_t* W16 = (ushort_t*)d_ws;
  ushort_t* xb  = W16;
  ushort_t* vb  = W16 + ND;
  ushort_t* S   = W16;
  ushort_t* hb  = W16;
  ushort_t* ff1 = W16 + ND;
  ushort_t* vt  = W16 + 2 * ND;
  ushort_t* ff2 = vt;
  ushort_t* wq  = W16 + 3 * ND;      // wq|wk|wv contiguous = fused [3072][1024]
  ushort_t* wf1 = wq + 3L * D * D;
  ushort_t* wf2 = wf1 + (long)D * D;
  ushort_t* qb = (ushort_t*)d_out;
  ushort_t* kb = qb + ND;
  ushort_t* attb = (ushort_t*)d_out;

  cast_f32_bf16<<<16384, 256, 0, stream>>>(x, xb, (int)(ND / 4));
  cast_w5<<<dim3(1024, 5), 256, 0, stream>>>(Wq, Wk, Wv, Wf1, Wf2, wq);

  // fused QKV: [16384,1024] @ [3072,1024]^T, epilogue routes to qb/kb/vb
  gemm256<0, 2, true><<<dim3(768), 512, 0, stream>>>(
      xb, 1024, wq, 1024, qb, kb, vb, 1024, nullptr, 1.f, 1024);

  transpose_bf16<<<dim3(16, 32, 8), 256, 0, stream>>>(vb, 1024, TD, vt, 2048, TD);

  // scores: S = Q K^T / 32, batch->XCD pinned triangular 256x128 tiles
  gemmA<0, 1, false><<<dim3(576), 512, 0, stream>>>(
      qb, 1024, TD, kb, 1024, TD, S, 2048, (long)T * T, nullptr, 0.03125f, 1024);

  softmax_sit<<<16384, 256, 0, stream>>>(S, sit);

  // att = P @ V, batch->XCD pinned heavy-first tiles, K=(by+1)*256
  gemmA<0, 2, true><<<dim3(512), 512, 0, stream>>>(
      S, 2048, (long)T * T, vt, 2048, TD, attb, 1024, TD, nullptr, 1.f, 2048);

  resid_ln<true, false><<<16384, 256, 0, stream>>>(attb, x, ln1g, ln1b, hb);

  gemm256<2, 1, false><<<dim3(4, 64), 512, 0, stream>>>(
      hb, 1024, wf1, 1024, ff1, ff1, ff1, 1024, bf1, 1.f, 1024);
  gemm256<1, 1, false><<<dim3(4, 64), 512, 0, stream>>>(
      ff1, 1024, wf2, 1024, ff2, ff2, ff2, 1024, bf2, 1.f, 1024);

  resid_ln<false, true><<<16384, 256, 0, stream>>>(ff2, hb, ln2g, ln2b, (float*)d_out);
}